// Round 6
// baseline (147.960 us; speedup 1.0000x reference)
//
#include <hip/hip_runtime.h>
#include <hip/hip_bf16.h>
#include <stdint.h>

// Problem constants (fixed by reference)
#define LQ   2048
#define NH   16
#define DD   128
#define NB   2
#define QBLK 128          // rows per block strip (8 waves x 16)
#define KBLK 64           // K/V tile rows
#define NQT  (LQ/QBLK)    // 16 strips
#define ROWSTR (NH*DD)    // 2048 floats between consecutive seq rows

typedef float f32x4 __attribute__((ext_vector_type(4)));
typedef short s16x4 __attribute__((ext_vector_type(4)));
typedef short s16x8 __attribute__((ext_vector_type(8)));

// scalar cast -> compiler packs into v_cvt_pk_bf16_f32 (m240)
__device__ __forceinline__ short f2bf(float f) {
  union { __hip_bfloat16 h; short s; } u;
  u.h = __float2bfloat16(f);
  return u.s;
}

__device__ __forceinline__ s16x4 cvt4(f32x4 x) {
  s16x4 r; r[0] = f2bf(x[0]); r[1] = f2bf(x[1]); r[2] = f2bf(x[2]); r[3] = f2bf(x[3]);
  return r;
}

__device__ __forceinline__ uint32_t lds_u32(const void* p) {
  return (uint32_t)(uint64_t)p;
}

// hardware transpose read (verified config): addr = subtile_base + 8*lane over a
// contiguous 128B-aligned [16][16] bf16 subtile -> lane gets col l15, rows 4*lhi+j
__device__ __forceinline__ s16x4 tr16(uint32_t addr) {
  s16x4 d;
  asm volatile("ds_read_b64_tr_b16 %0, %1" : "=v"(d) : "v"(addr) : "memory");
  return d;
}

struct Stage { f32x4 k[4]; f32x4 v[4]; };

__device__ __forceinline__ Stage load_tile(const float* __restrict__ Kg,
                                           const float* __restrict__ Vg,
                                           int s0, int tid) {
  Stage st;
  const int rk = tid >> 5;          // 0..15
  const int c4 = tid & 31;
#pragma unroll
  for (int j = 0; j < 4; ++j)
    st.k[j] = *(const f32x4*)(Kg + (size_t)(s0 + rk + 16 * j) * ROWSTR + 4 * c4);
#pragma unroll
  for (int p = 0; p < 4; ++p) {
    const int g = tid + 512 * p;
    const int rv = (g & 3) | ((g >> 7) << 2);   // 0..63, bijective
    const int cv = (g >> 2) & 31;
    st.v[p] = *(const f32x4*)(Vg + (size_t)(s0 + rv) * ROWSTR + 4 * cv);
  }
  return st;
}

__device__ __forceinline__ void write_tile(short* Kb, short* Vb,
                                           const Stage& st, int tid) {
  const int rk = tid >> 5;
  const int c4 = tid & 31;
  // K row-major padded 132 (66 dwords = 2 mod 32: measured conflict-free)
#pragma unroll
  for (int j = 0; j < 4; ++j)
    *(s16x4*)&Kb[(rk + 16 * j) * 132 + 4 * c4] = cvt4(st.k[j]);
#pragma unroll
  for (int p = 0; p < 4; ++p) {
    const int g = tid + 512 * p;
    const int rv = (g & 3) | ((g >> 7) << 2);
    const int cv = (g >> 2) & 31;
    const int sub = (rv >> 4) * 8 + (cv >> 2);   // s_hi*8 + d_blk, 0..31
    *(s16x4*)&Vb[sub * 256 + (rv & 15) * 16 + 4 * (cv & 3)] = cvt4(st.v[p]);
  }
}

__global__ __launch_bounds__(512, 2) void qattn_fwd(
    const float* __restrict__ keys, const float* __restrict__ values,
    float* __restrict__ out)
{
  __shared__ short K_lds[2][KBLK * 132];   // row-major padded 132 (16.5 KB ea)
  __shared__ short V_lds[2][32 * 256];     // 32x [16][16] subtiles (16 KB ea)

  const int tid  = threadIdx.x;
  const int wid  = tid >> 6;      // 0..7 waves
  const int lane = tid & 63;
  const int l15  = lane & 15;
  const int lhi  = lane >> 4;     // 0..3

  // 512 blocks, one strip each; 2 co-resident blocks per CU.
  // Slot->strip map balances BOTH plausible co-residency pairings:
  // (i, i+256) and (2t, 2t+1) each give qt + (15-qt) -> constant 36 tiles/CU.
  const int wg   = blockIdx.x;
  const int x    = wg & 7;          // XCD under round-robin dispatch
  const int s    = wg >> 3;         // per-XCD slot 0..63
  const int u    = (s & 31) >> 1;
  const int base = (s & 1) ? (15 - u) : u;
  const int qt   = (s < 32) ? base : (15 - base);
  const int rr   = ((s >= 32) ? 2 : 0) + (s & 1);
  const int bh   = x + 8 * rr;
  const int b    = bh >> 4;
  const int h    = bh & 15;
  const int q0   = qt * QBLK;
  const int nt   = 2 * qt + 2;      // 64-row tiles covering s <= q0+127

  const float* Kg = keys   + ((size_t)b * LQ * ROWSTR) + (size_t)h * DD;
  const float* Vg = values + ((size_t)b * LQ * ROWSTR) + (size_t)h * DD;
  float*       Og = out    + ((size_t)b * LQ * ROWSTR) + (size_t)h * DD;

  // logits * (0.5/sqrt(128)) * log2(e); folded into Q fragments.
  // quantum_score cancels in softmax (uniform shift).
  const float CS = 0.5f * 0.08838834764831845f * 1.4426950408889634f;

  // ---- Q fragments (Q := values rows), CS pre-folded, f32 -> bf16 regs ----
  const int qg = q0 + wid * 16 + l15;     // this lane's q-row
  const float* Qrow = Vg + (size_t)qg * ROWSTR;
  s16x8 qf[4];
#pragma unroll
  for (int c = 0; c < 4; ++c) {
    f32x4 lo = *(const f32x4*)(Qrow + 32 * c + 4 * lhi);
    f32x4 hi = *(const f32x4*)(Qrow + 32 * c + 16 + 4 * lhi);
    lo *= CS; hi *= CS;
    qf[c] = __builtin_shufflevector(cvt4(lo), cvt4(hi), 0, 1, 2, 3, 4, 5, 6, 7);
  }

  f32x4 o[8];
#pragma unroll
  for (int i = 0; i < 8; ++i) o[i] = f32x4{0.f, 0.f, 0.f, 0.f};
  float m  = -1e30f;   // running max (exp2-logit units), keyed by q = l15
  float ll = 0.0f;
  const int q_wave_hi = q0 + wid * 16 + 15;

  // ---- prologue: stage tile 0 into buf 0 ----
  {
    Stage st = load_tile(Kg, Vg, 0, tid);
    write_tile(K_lds[0], V_lds[0], st, tid);
  }
  __syncthreads();

  for (int t = 0; t < nt; ++t) {
    const int cur = t & 1;
    const int s0  = t * KBLK;

    // issue next tile's global loads early (latency hides under compute)
    Stage st;
    const bool more = (t + 1) < nt;
    if (more) st = load_tile(Kg, Vg, (t + 1) * KBLK, tid);

    if (s0 <= q_wave_hi) {                 // per-wave causal skip
      const short* Kb = K_lds[cur];
      short*       Vb = V_lds[cur];

      // ---- QK^T swapped: sT[sb] = K_sb · Q^T -> S^T[s][q] ----
      f32x4 sT[4];
#pragma unroll
      for (int sb = 0; sb < 4; ++sb) sT[sb] = f32x4{0.f, 0.f, 0.f, 0.f};
      __builtin_amdgcn_s_setprio(1);
#pragma unroll
      for (int c = 0; c < 4; ++c) {
#pragma unroll
        for (int sb = 0; sb < 4; ++sb) {
          s16x4 a  = *(const s16x4*)&Kb[(sb * 16 + l15) * 132 + 32 * c + 4 * lhi];
          s16x4 bb = *(const s16x4*)&Kb[(sb * 16 + l15) * 132 + 32 * c + 16 + 4 * lhi];
          s16x8 kf = __builtin_shufflevector(a, bb, 0, 1, 2, 3, 4, 5, 6, 7);
          sT[sb] = __builtin_amdgcn_mfma_f32_16x16x32_bf16(kf, qf[c], sT[sb], 0, 0, 0);
        }
      }
      __builtin_amdgcn_s_setprio(0);

      // ---- online softmax: lane owns q=l15, s = s0 + sb*16 + 4*lhi + r ----
      if (s0 + KBLK - 1 > qg) {            // diagonal tile: causal mask
#pragma unroll
        for (int sb = 0; sb < 4; ++sb)
#pragma unroll
          for (int r = 0; r < 4; ++r)
            if (s0 + sb * 16 + 4 * lhi + r > qg) sT[sb][r] = -1e30f;
      }
      float tm = sT[0][0];
#pragma unroll
      for (int sb = 0; sb < 4; ++sb)
#pragma unroll
        for (int r = 0; r < 4; ++r) tm = fmaxf(tm, sT[sb][r]);
      tm = fmaxf(tm, __shfl_xor(tm, 16));
      tm = fmaxf(tm, __shfl_xor(tm, 32));

      // defer-max (T13): only rescale when max grew past THR=8 (exp2 units)
      if (!__all(tm - m <= 8.0f)) {
        const float mn = fmaxf(m, tm);
        const float alpha = exp2f(m - mn);
        m = mn;
        float ar[4];
#pragma unroll
        for (int r = 0; r < 4; ++r) ar[r] = __shfl(alpha, 4 * lhi + r);
#pragma unroll
        for (int df = 0; df < 8; ++df)
#pragma unroll
          for (int r = 0; r < 4; ++r) o[df][r] *= ar[r];
        ll *= alpha;
      }
      float rs = 0.f;
      s16x8 pf0, pf1;
#pragma unroll
      for (int sb = 0; sb < 2; ++sb)
#pragma unroll
        for (int r = 0; r < 4; ++r) {
          float p = exp2f(sT[sb][r] - m);
          rs += p;
          pf0[sb * 4 + r] = f2bf(p);
        }
#pragma unroll
      for (int sb = 0; sb < 2; ++sb)
#pragma unroll
        for (int r = 0; r < 4; ++r) {
          float p = exp2f(sT[2 + sb][r] - m);
          rs += p;
          pf1[sb * 4 + r] = f2bf(p);
        }
      rs += __shfl_xor(rs, 16);
      rs += __shfl_xor(rs, 32);
      ll += rs;

      // ---- PV via hardware transpose reads, two 32-row k-slots ----
      const uint32_t vbase = lds_u32(&Vb[0]) + 8u * (uint32_t)lane;
#pragma unroll
      for (int ks = 0; ks < 2; ++ks) {
        s16x4 vlo[8], vhi[8];
#pragma unroll
        for (int df = 0; df < 8; ++df) {
          vlo[df] = tr16(vbase + 512u * (uint32_t)(16 * ks + df));
          vhi[df] = tr16(vbase + 512u * (uint32_t)(16 * ks + 8 + df));
        }
        asm volatile("s_waitcnt lgkmcnt(0)" ::: "memory");
        __builtin_amdgcn_sched_barrier(0);
        const s16x8 pf = ks ? pf1 : pf0;
        __builtin_amdgcn_s_setprio(1);
#pragma unroll
        for (int df = 0; df < 8; ++df) {
          s16x8 vf = __builtin_shufflevector(vlo[df], vhi[df], 0, 1, 2, 3, 4, 5, 6, 7);
          o[df] = __builtin_amdgcn_mfma_f32_16x16x32_bf16(pf, vf, o[df], 0, 0, 0);
        }
        __builtin_amdgcn_s_setprio(0);
      }
    }

    // write next tile into the other buffer (compiler inserts vmcnt wait)
    if (more) write_tile(K_lds[cur ^ 1], V_lds[cur ^ 1], st, tid);
    __syncthreads();                       // single barrier per tile
  }

  // ---- epilogue: O /= l, store f32 ----
  const float linv = 1.0f / ll;
#pragma unroll
  for (int r = 0; r < 4; ++r) {
    const float lr = __shfl(linv, 4 * lhi + r);
    float* orow = Og + (size_t)(q0 + wid * 16 + 4 * lhi + r) * ROWSTR;
#pragma unroll
    for (int df = 0; df < 8; ++df)
      orow[df * 16 + l15] = o[df][r] * lr;
  }
}

extern "C" void kernel_launch(void* const* d_in, const int* in_sizes, int n_in,
                              void* d_out, int out_size, void* d_ws, size_t ws_size,
                              hipStream_t stream) {
  // inputs: 0=queries (dead), 1=keys, 2=values, 3=q_params (dead: softmax shift)
  const float* keys   = (const float*)d_in[1];
  const float* values = (const float*)d_in[2];
  float*       out    = (float*)d_out;
  dim3 grid(2 * NB * NH * (NQT / 2));   // 512 blocks: 2 complementary per CU
  dim3 block(512);
  hipLaunchKernelGGL(qattn_fwd, grid, block, 0, stream, keys, values, out);
}

// Round 8
// 90.380 us; speedup vs baseline: 1.6371x; 1.6371x over previous
//
#include <hip/hip_runtime.h>
#include <hip/hip_bf16.h>
#include <stdint.h>

// Problem constants (fixed by reference)
#define LQ   2048
#define NH   16
#define DD   128
#define NB   2
#define QBLK 128          // q-rows per block strip
#define KBLK 64           // K/V tile rows (split 32/32 across two teams)
#define NQT  (LQ/QBLK)    // 16 strips; paired qt <-> 15-qt for balance
#define ROWSTR (NH*DD)    // 2048 floats between consecutive seq rows
#define KTILE (KBLK*132)  // 8448 shorts per K tile buffer
#define VTILE (32*256)    // 8192 shorts per V tile buffer

typedef float f32x4 __attribute__((ext_vector_type(4)));
typedef short s16x4 __attribute__((ext_vector_type(4)));
typedef short s16x8 __attribute__((ext_vector_type(8)));

// scalar cast -> compiler packs into v_cvt_pk_bf16_f32 (m240)
__device__ __forceinline__ short f2bf(float f) {
  union { __hip_bfloat16 h; short s; } u;
  u.h = __float2bfloat16(f);
  return u.s;
}

__device__ __forceinline__ s16x4 cvt4(f32x4 x) {
  s16x4 r; r[0] = f2bf(x[0]); r[1] = f2bf(x[1]); r[2] = f2bf(x[2]); r[3] = f2bf(x[3]);
  return r;
}

__device__ __forceinline__ uint32_t lds_u32(const void* p) {
  return (uint32_t)(uint64_t)p;
}

// hardware transpose read (verified config): addr = subtile_base + 8*lane over a
// contiguous 128B-aligned [16][16] bf16 subtile -> lane gets col l15, rows 4*lhi+j
__device__ __forceinline__ s16x4 tr16(uint32_t addr) {
  s16x4 d;
  asm volatile("ds_read_b64_tr_b16 %0, %1" : "=v"(d) : "v"(addr) : "memory");
  return d;
}

struct Stage { f32x4 k[4]; f32x4 v[4]; };

__device__ __forceinline__ Stage load_tile(const float* __restrict__ Kg,
                                           const float* __restrict__ Vg,
                                           int s0, int tid) {
  Stage st;
  const int rk = tid >> 5;          // 0..15
  const int c4 = tid & 31;
#pragma unroll
  for (int j = 0; j < 4; ++j)
    st.k[j] = *(const f32x4*)(Kg + (size_t)(s0 + rk + 16 * j) * ROWSTR + 4 * c4);
#pragma unroll
  for (int p = 0; p < 4; ++p) {
    const int g = tid + 512 * p;
    const int rv = (g & 3) | ((g >> 7) << 2);   // 0..63, bijective
    const int cv = (g >> 2) & 31;
    st.v[p] = *(const f32x4*)(Vg + (size_t)(s0 + rv) * ROWSTR + 4 * cv);
  }
  return st;
}

__device__ __forceinline__ void write_tile(short* Kb, short* Vb,
                                           const Stage& st, int tid) {
  const int rk = tid >> 5;
  const int c4 = tid & 31;
  // K row-major padded 132 (measured conflict-free)
#pragma unroll
  for (int j = 0; j < 4; ++j)
    *(s16x4*)&Kb[(rk + 16 * j) * 132 + 4 * c4] = cvt4(st.k[j]);
#pragma unroll
  for (int p = 0; p < 4; ++p) {
    const int g = tid + 512 * p;
    const int rv = (g & 3) | ((g >> 7) << 2);
    const int cv = (g >> 2) & 31;
    const int sub = (rv >> 4) * 8 + (cv >> 2);   // s_hi*8 + d_blk, 0..31
    *(s16x4*)&Vb[sub * 256 + (rv & 15) * 16 + 4 * (cv & 3)] = cvt4(st.v[p]);
  }
}

__global__ __launch_bounds__(512, 2) void qattn_fwd(
    const float* __restrict__ keys, const float* __restrict__ values,
    float* __restrict__ out)
{
  // one block of shared memory, overlaid: tiles during the loop, merge at strip end
  __shared__ short SM[2 * KTILE + 2 * VTILE];       // 66,560 B

  const int tid  = threadIdx.x;
  const int wid  = tid >> 6;      // 0..7 waves
  const int lane = tid & 63;
  const int l15  = lane & 15;
  const int lhi  = lane >> 4;     // 0..3
  const int team = wid >> 2;      // 0: s-rows 0-31 of each tile, 1: rows 32-63
  const int tw   = wid & 3;       // wave-in-team: owns q-rows tw*32 .. tw*32+31

  // round-4 proven map: 256 blocks, two complementary strips each
  const int wg   = blockIdx.x;
  const int bh   = wg & 31;
  const int pair = wg >> 5;             // 0..7
  const int b    = bh >> 4;
  const int h    = bh & 15;

  const float* Kg = keys   + ((size_t)b * LQ * ROWSTR) + (size_t)h * DD;
  const float* Vg = values + ((size_t)b * LQ * ROWSTR) + (size_t)h * DD;
  float*       Og = out    + ((size_t)b * LQ * ROWSTR) + (size_t)h * DD;

  // logits * (0.5/sqrt(128)) * log2(e); folded into Q fragments.
  // quantum_score cancels in softmax (uniform shift).
  const float CS = 0.5f * 0.08838834764831845f * 1.4426950408889634f;
  const int soff = 32 * team;     // team's s offset within each 64-row tile

  for (int sp = 0; sp < 2; ++sp) {
    const int qt = sp ? (NQT - 1 - pair) : pair;
    const int q0 = qt * QBLK;
    const int nt = 2 * qt + 2;            // 64-row tiles covering s <= q0+127

    // ---- Q fragments for both q-halves (Q := values rows), CS pre-folded ----
    int qg[2];
    s16x8 qf[2][4];
#pragma unroll
    for (int qh = 0; qh < 2; ++qh) {
      qg[qh] = q0 + tw * 32 + qh * 16 + l15;
      const float* Qrow = Vg + (size_t)qg[qh] * ROWSTR;
#pragma unroll
      for (int c = 0; c < 4; ++c) {
        f32x4 lo = *(const f32x4*)(Qrow + 32 * c + 4 * lhi);
        f32x4 hi = *(const f32x4*)(Qrow + 32 * c + 16 + 4 * lhi);
        lo *= CS; hi *= CS;
        qf[qh][c] = __builtin_shufflevector(cvt4(lo), cvt4(hi), 0, 1, 2, 3, 4, 5, 6, 7);
      }
    }

    f32x4 o[2][8];
#pragma unroll
    for (int qh = 0; qh < 2; ++qh)
#pragma unroll
      for (int i = 0; i < 8; ++i) o[qh][i] = f32x4{0.f, 0.f, 0.f, 0.f};
    float m[2]  = { -1e30f, -1e30f };   // running max (exp2 units), keyed q=l15
    float ll[2] = { 0.f, 0.f };
    const int q_wave_hi = q0 + tw * 32 + 31;

    // ---- prologue: stage tile 0 into buf 0 ----
    {
      Stage st = load_tile(Kg, Vg, 0, tid);
      if (sp) __syncthreads();           // prior strip's merge readers done
      write_tile(SM, SM + 2 * KTILE, st, tid);
    }
    __syncthreads();

    for (int t = 0; t < nt; ++t) {
      const int cur = t & 1;
      const int s0t = t * KBLK + soff;   // this team's s-range start

      Stage st;
      const bool more = (t + 1) < nt;
      if (more) st = load_tile(Kg, Vg, (t + 1) * KBLK, tid);

      if (s0t <= q_wave_hi) {            // per-wave causal skip
        const short* Kb = SM + cur * KTILE;
        const short* Vb = SM + 2 * KTILE + cur * VTILE;

        // ---- QK^T swapped: K-frags read ONCE, used for both q-halves ----
        f32x4 sT[2][2];
#pragma unroll
        for (int qh = 0; qh < 2; ++qh)
#pragma unroll
          for (int sb = 0; sb < 2; ++sb) sT[qh][sb] = f32x4{0.f, 0.f, 0.f, 0.f};
        __builtin_amdgcn_s_setprio(1);
#pragma unroll
        for (int c = 0; c < 4; ++c) {
#pragma unroll
          for (int sb = 0; sb < 2; ++sb) {
            s16x4 a  = *(const s16x4*)&Kb[(soff + sb * 16 + l15) * 132 + 32 * c + 4 * lhi];
            s16x4 bb = *(const s16x4*)&Kb[(soff + sb * 16 + l15) * 132 + 32 * c + 16 + 4 * lhi];
            s16x8 kf = __builtin_shufflevector(a, bb, 0, 1, 2, 3, 4, 5, 6, 7);
            sT[0][sb] = __builtin_amdgcn_mfma_f32_16x16x32_bf16(kf, qf[0][c], sT[0][sb], 0, 0, 0);
            sT[1][sb] = __builtin_amdgcn_mfma_f32_16x16x32_bf16(kf, qf[1][c], sT[1][sb], 0, 0, 0);
          }
        }
        __builtin_amdgcn_s_setprio(0);

        // ---- V tr-reads issued early (latency hides under softmax) ----
        const uint32_t vbase = lds_u32(Vb) + 8u * (uint32_t)lane
                             + 512u * (uint32_t)(16 * team);
        s16x4 vlo[8], vhi[8];
#pragma unroll
        for (int df = 0; df < 8; ++df) {
          vlo[df] = tr16(vbase + 512u * (uint32_t)df);        // s_local 0-15
          vhi[df] = tr16(vbase + 512u * (uint32_t)(8 + df));  // s_local 16-31
        }

        // ---- online softmax per q-half: lane owns q=qg[qh], s = s0t+sb*16+4*lhi+r
        s16x8 pf[2];
#pragma unroll
        for (int qh = 0; qh < 2; ++qh) {
          if (s0t + 31 > qg[qh]) {       // diagonal: causal mask
#pragma unroll
            for (int sb = 0; sb < 2; ++sb)
#pragma unroll
              for (int r = 0; r < 4; ++r)
                if (s0t + sb * 16 + 4 * lhi + r > qg[qh]) sT[qh][sb][r] = -1e30f;
          }
          float tm = sT[qh][0][0];
#pragma unroll
          for (int sb = 0; sb < 2; ++sb)
#pragma unroll
            for (int r = 0; r < 4; ++r) tm = fmaxf(tm, sT[qh][sb][r]);
          tm = fmaxf(tm, __shfl_xor(tm, 16));
          tm = fmaxf(tm, __shfl_xor(tm, 32));

          // defer-max (T13): rescale only when max grew past THR=8
          if (!__all(tm - m[qh] <= 8.0f)) {
            const float mn = fmaxf(m[qh], tm);
            const float alpha = exp2f(m[qh] - mn);
            m[qh] = mn;
            float ar[4];
#pragma unroll
            for (int r = 0; r < 4; ++r) ar[r] = __shfl(alpha, 4 * lhi + r);
#pragma unroll
            for (int df = 0; df < 8; ++df)
#pragma unroll
              for (int r = 0; r < 4; ++r) o[qh][df][r] *= ar[r];
            ll[qh] *= alpha;
          }
          float rs = 0.f;
#pragma unroll
          for (int sb = 0; sb < 2; ++sb)
#pragma unroll
            for (int r = 0; r < 4; ++r) {
              float p = exp2f(sT[qh][sb][r] - m[qh]);
              rs += p;
              pf[qh][sb * 4 + r] = f2bf(p);
            }
          rs += __shfl_xor(rs, 16);
          rs += __shfl_xor(rs, 32);
          ll[qh] += rs;
        }

        // ---- PV: V-frags used for both q-halves ----
        asm volatile("s_waitcnt lgkmcnt(0)" ::: "memory");
        __builtin_amdgcn_sched_barrier(0);
        __builtin_amdgcn_s_setprio(1);
#pragma unroll
        for (int df = 0; df < 8; ++df) {
          s16x8 vf = __builtin_shufflevector(vlo[df], vhi[df], 0, 1, 2, 3, 4, 5, 6, 7);
          o[0][df] = __builtin_amdgcn_mfma_f32_16x16x32_bf16(pf[0], vf, o[0][df], 0, 0, 0);
          o[1][df] = __builtin_amdgcn_mfma_f32_16x16x32_bf16(pf[1], vf, o[1][df], 0, 0, 0);
        }
        __builtin_amdgcn_s_setprio(0);
      }

      if (more) write_tile(SM + (cur ^ 1) * KTILE,
                           SM + 2 * KTILE + (cur ^ 1) * VTILE, st, tid);
      __syncthreads();                   // single barrier per tile
    }

    // ---- strip-end merge: combine team A (s low-half) with team B ----
    {
      float* LM_O  = (float*)SM;                 // [128][128] f32 overlay
      float* LM_ml = (float*)SM + 128 * 128;     // [2][128]: m then l
      if (team == 1) {
#pragma unroll
        for (int qh = 0; qh < 2; ++qh) {
#pragma unroll
          for (int r = 0; r < 4; ++r) {
            const int qloc = tw * 32 + qh * 16 + 4 * lhi + r;
#pragma unroll
            for (int df = 0; df < 8; ++df)
              LM_O[qloc * 128 + df * 16 + l15] = o[qh][df][r];
          }
          if (lhi == 0) {
            LM_ml[tw * 32 + qh * 16 + l15]       = m[qh];
            LM_ml[128 + tw * 32 + qh * 16 + l15] = ll[qh];
          }
        }
      }
      __syncthreads();
      if (team == 0) {
#pragma unroll
        for (int qh = 0; qh < 2; ++qh) {
#pragma unroll
          for (int r = 0; r < 4; ++r) {
            const int qloc = tw * 32 + qh * 16 + 4 * lhi + r;
            const float mA = __shfl(m[qh], 4 * lhi + r);
            const float lA = __shfl(ll[qh], 4 * lhi + r);
            const float mB = LM_ml[qloc];
            const float lB = LM_ml[128 + qloc];
            const float ms = fmaxf(mA, mB);
            const float aA = exp2f(mA - ms);
            const float aB = exp2f(mB - ms);
            const float inv = 1.0f / (lA * aA + lB * aB);
            const float cA = aA * inv, cB = aB * inv;
            float* orow = Og + (size_t)(q0 + qloc) * ROWSTR;
#pragma unroll
            for (int df = 0; df < 8; ++df)
              orow[df * 16 + l15] = o[qh][df][r] * cA
                                  + LM_O[qloc * 128 + df * 16 + l15] * cB;
          }
        }
      }
      // next strip's prologue barrier (sp==1) protects LM from re-staging
    }
  }
}

extern "C" void kernel_launch(void* const* d_in, const int* in_sizes, int n_in,
                              void* d_out, int out_size, void* d_ws, size_t ws_size,
                              hipStream_t stream) {
  // inputs: 0=queries (dead), 1=keys, 2=values, 3=q_params (dead: softmax shift)
  const float* keys   = (const float*)d_in[1];
  const float* values = (const float*)d_in[2];
  float*       out    = (float*)d_out;
  dim3 grid(NB * NH * (NQT / 2));   // 256 blocks: one per CU, perfectly balanced
  dim3 block(512);
  hipLaunchKernelGGL(qattn_fwd, grid, block, 0, stream, keys, values, out);
}